// Round 1
// baseline (422.947 us; speedup 1.0000x reference)
//
#include <hip/hip_runtime.h>

// LSTMCell with attention, MI355X gfx950.
// Round 5: port fused GEMM to the 256^2 8-wave phase-split schedule:
//  - 512-thread blocks, tile 256 rows x 64 hidden cols (x4 gates / x2 att slices)
//  - full LDS double buffer (128KB), raw s_barrier (no vmcnt(0) drain)
//  - counted s_waitcnt vmcnt(8)/(2) once per K-tile, prefetch stays in flight
//  - setprio(1) around each 16-MFMA quadrant, XCD-bijective block swizzle
//  - per-phase quadrants: P1 rf0-3 x cf0-1, P2 rf0-3 x cf2-3, P3 rf4-7 x cf2-3,
//    P4 rf4-7 x cf0-1 (bLo kept live P1->P4; B LDS free after P2, A after P3,
//    so stage-B issues at P3 and stage-A at P4 are WAR-safe region-wise).

typedef __attribute__((ext_vector_type(8))) __bf16 bf16x8;
typedef __attribute__((ext_vector_type(8))) unsigned short ushort8;
typedef __attribute__((ext_vector_type(4))) float f32x4;

#define AS1 __attribute__((address_space(1)))
#define AS3 __attribute__((address_space(3)))

__device__ __forceinline__ void gld16(const unsigned short* g, unsigned short* l) {
    __builtin_amdgcn_global_load_lds((const AS1 void*)g, (AS3 void*)l, 16, 0, 0);
}

__device__ __forceinline__ unsigned short f2bf(float f) {
    unsigned int u = __builtin_bit_cast(unsigned int, f);
    u += 0x7fffu + ((u >> 16) & 1u);   // RNE
    return (unsigned short)(u >> 16);
}

__device__ __forceinline__ float sigmoidf_(float x) { return 1.f / (1.f + __expf(-x)); }
__device__ __forceinline__ float tanhf_(float x) {
    float e = __expf(-2.f * fabsf(x));
    float t = (1.f - e) / (1.f + e);
    return x >= 0.f ? t : -t;
}

__device__ __forceinline__ bf16x8 ldfrag(const unsigned short* p) {
    return __builtin_bit_cast(bf16x8, *(const ushort8*)p);
}

#define BARRIER __builtin_amdgcn_s_barrier()
#define LGKM0   asm volatile("s_waitcnt lgkmcnt(0)" ::: "memory")
#define VMW_(n) asm volatile("s_waitcnt vmcnt(" #n ")" ::: "memory")
#define VMW(n)  VMW_(n)
#define MFMA16(a, b, c) __builtin_amdgcn_mfma_f32_16x16x32_bf16(a, b, c, 0, 0, 0)

// ---------------- fused cast/pack + bias kernel (BW-bound, ~33us) ----------------
__global__ void cast_all_k(const float* __restrict__ input, const float* __restrict__ hx,
                           const float* __restrict__ att,   const float* __restrict__ w_ih,
                           const float* __restrict__ w_hh,  const float* __restrict__ w_att,
                           const float* __restrict__ b_ih,  const float* __restrict__ b_hh,
                           unsigned short* __restrict__ XH, unsigned short* __restrict__ ATTb,
                           unsigned short* __restrict__ W4, unsigned short* __restrict__ WA,
                           float* __restrict__ bias4)
{
    int gid = blockIdx.x * blockDim.x + threadIdx.x;
    if (gid < 4096) bias4[gid] = b_ih[gid] + b_hh[gid];
    const int total = 4456448;  // total float8 units
    for (int i = gid; i < total; i += gridDim.x * blockDim.x) {
        const float* src; unsigned short* dst; int ld, off, rel;
        if (i < 1048576)      { src = input; dst = XH;   ld = 2048; off = 0;    rel = i; }
        else if (i < 2097152) { src = hx;    dst = XH;   ld = 2048; off = 1024; rel = i - 1048576; }
        else if (i < 3145728) { src = att;   dst = ATTb; ld = 1024; off = 0;    rel = i - 2097152; }
        else if (i < 3670016) { src = w_ih;  dst = W4;   ld = 2048; off = 0;    rel = i - 3145728; }
        else if (i < 4194304) { src = w_hh;  dst = W4;   ld = 2048; off = 1024; rel = i - 3670016; }
        else                  { src = w_att; dst = WA;   ld = 1024; off = 0;    rel = i - 4194304; }
        int e = rel * 8;
        int r = e >> 10, c = e & 1023;   // all sources have 1024 fp32 cols
        const float4 v0 = *(const float4*)(src + e);
        const float4 v1 = *(const float4*)(src + e + 4);
        ushort8 p;
        p[0] = f2bf(v0.x); p[1] = f2bf(v0.y); p[2] = f2bf(v0.z); p[3] = f2bf(v0.w);
        p[4] = f2bf(v1.x); p[5] = f2bf(v1.y); p[6] = f2bf(v1.z); p[7] = f2bf(v1.w);
        *(ushort8*)(dst + r * ld + off + c) = p;
    }
}

// ---------------- fused GEMM + full LSTM epilogue (8-phase schedule) ----------------
// Block: rows row0..row0+255, hidden cols n0..n0+63.
// Wave (wr,wn): rows wr*128..+127, hidden cols n0+wn*16..+15; all 4 gates / 2 att
// slices for those cols live in-wave (B tile row = wn*64 + gate*16 + l15, resp.
// wn*32 + slice*16 + l15) so the whole epilogue is register-local.
// LDS chunk swizzle: tile chunk L holds global k-chunk (L&7)^(row&7) of row L>>3;
// fragment read for k-slot g: row*64 + (g^(row&7))*8.
__global__ __launch_bounds__(512, 2) void fused_gemm_k(
    const unsigned short* __restrict__ XH, const unsigned short* __restrict__ W4,
    const unsigned short* __restrict__ ATTb, const unsigned short* __restrict__ WA,
    const float* __restrict__ bias4, const float* __restrict__ bias_att,
    const float* __restrict__ cx, float* __restrict__ out)
{
    __shared__ unsigned short As[2][16384];   // 2 x 32KB
    __shared__ unsigned short Bs[2][16384];   // 2 x 32KB

    const int tid  = threadIdx.x;
    const int wave = tid >> 6, lane = tid & 63;
    const int l15 = lane & 15, quad = lane >> 4;
    const int wr = wave >> 2, wn = wave & 3;

    // bijective XCD swizzle (512 % 8 == 0): each XCD owns 2 by-panels of W4/WA.
    const int orig = blockIdx.x;
    const int wg   = (orig & 7) * 64 + (orig >> 3);
    const int row0 = (wg & 31) * 256;
    const int n0   = (wg >> 5) * 64;

    // ---- staging geometry: thread t stages chunk L = tid + p*512 of each half
    const int rl = tid >> 3;                         // 0..63
    const int c8 = (tid & 7) ^ (rl & 7);             // source k-chunk (swizzled)
    unsigned aG = (unsigned)(row0 + rl) * 2048u + (unsigned)c8 * 8u;
    unsigned bG = (unsigned)(((rl >> 4) & 3) * 1024 + n0 + (rl & 15)) * 2048u + (unsigned)c8 * 8u;
    unsigned aA = (unsigned)(row0 + rl) * 1024u + (unsigned)c8 * 8u;
    unsigned bA = (unsigned)(((rl >> 4) & 1) * 1024 + n0 + ((rl >> 5) & 1) * 16 + (rl & 15)) * 1024u
                  + (unsigned)c8 * 8u;

    auto stageA_att = [&](int buf) {   // 4 loads: full 256x64 A tile of next att k-tile
#pragma unroll
        for (int h = 0; h < 2; ++h)
#pragma unroll
            for (int p = 0; p < 2; ++p)
                gld16(ATTb + aA + (unsigned)(h * 131072 + p * 65536),
                      &As[buf][h * 8192 + (tid + p * 512) * 8]);
        aA += 64;
    };
    auto stageB_att = [&](int buf) {   // 2 loads: 128x64 B tile
#pragma unroll
        for (int h = 0; h < 2; ++h)
            gld16(WA + bA + (unsigned)(h * 32768), &Bs[buf][(h * 512 + tid) * 8]);
        bA += 64;
    };
    auto stageA_g = [&](int buf) {     // 4 loads: 256x64 A tile
#pragma unroll
        for (int h = 0; h < 2; ++h)
#pragma unroll
            for (int p = 0; p < 2; ++p)
                gld16(XH + aG + (unsigned)(h * 262144 + p * 131072),
                      &As[buf][h * 8192 + (tid + p * 512) * 8]);
        aG += 64;
    };
    auto stageB_g = [&](int buf) {     // 4 loads: 256x64 B tile
#pragma unroll
        for (int h = 0; h < 2; ++h)
#pragma unroll
            for (int p = 0; p < 2; ++p)
                gld16(W4 + bG + (unsigned)(h * 65536 + p * 32768),
                      &Bs[buf][h * 8192 + (tid + p * 512) * 8]);
        bG += 64;
    };

    // fragment read constants (lane-local)
    const int swz0 = (quad ^ (l15 & 7)) * 8;
    const int swz1 = ((4 + quad) ^ (l15 & 7)) * 8;
    const int aro  = (wr * 128 + l15) * 64;
    const int brG  = (wn * 64 + l15) * 64;
    const int brA  = (wn * 32 + l15) * 64;

    const f32x4 z = {0.f, 0.f, 0.f, 0.f};

    // ================= phase A: att GEMM, K=1024 (16 tiles of BK=64) =================
    f32x4 acc2[8][2];
#pragma unroll
    for (int i = 0; i < 8; ++i) { acc2[i][0] = z; acc2[i][1] = z; }

    auto att_group = [&](int buf, bool issA, bool issB) {
        bf16x8 aF[4][2], bLo[2][2];
        // P1: read A rf0-3 + B, issue next A
#pragma unroll
        for (int i = 0; i < 4; ++i) {
            aF[i][0] = ldfrag(&As[buf][aro + i * 1024 + swz0]);
            aF[i][1] = ldfrag(&As[buf][aro + i * 1024 + swz1]);
        }
#pragma unroll
        for (int j = 0; j < 2; ++j) {
            bLo[j][0] = ldfrag(&Bs[buf][brA + j * 1024 + swz0]);
            bLo[j][1] = ldfrag(&Bs[buf][brA + j * 1024 + swz1]);
        }
        if (issA) stageA_att(buf ^ 1);
        BARRIER; LGKM0;
        __builtin_amdgcn_s_setprio(1);
#pragma unroll
        for (int i = 0; i < 4; ++i)
#pragma unroll
            for (int j = 0; j < 2; ++j) {
                acc2[i][j] = MFMA16(aF[i][0], bLo[j][0], acc2[i][j]);
                acc2[i][j] = MFMA16(aF[i][1], bLo[j][1], acc2[i][j]);
            }
        __builtin_amdgcn_s_setprio(0);
        BARRIER;
        // P2: read A rf4-7, issue B of tile t+2 (B LDS free after P1)
#pragma unroll
        for (int i = 0; i < 4; ++i) {
            aF[i][0] = ldfrag(&As[buf][aro + (4 + i) * 1024 + swz0]);
            aF[i][1] = ldfrag(&As[buf][aro + (4 + i) * 1024 + swz1]);
        }
        if (issB) stageB_att(buf);
        BARRIER; LGKM0;
        __builtin_amdgcn_s_setprio(1);
#pragma unroll
        for (int i = 0; i < 4; ++i)
#pragma unroll
            for (int j = 0; j < 2; ++j) {
                acc2[4 + i][j] = MFMA16(aF[i][0], bLo[j][0], acc2[4 + i][j]);
                acc2[4 + i][j] = MFMA16(aF[i][1], bLo[j][1], acc2[4 + i][j]);
            }
        __builtin_amdgcn_s_setprio(0);
    };

    stageA_att(0); stageB_att(0); stageB_att(1);   // A0,B0 then B1
    VMW(2); BARRIER;                               // A0,B0 landed; B1 in flight
#pragma unroll 2
    for (int t = 0; t < 14; ++t) {
        att_group(t & 1, true, true);
        VMW(2); BARRIER;                           // tile t+1 landed; B(t+2) in flight
    }
    att_group(0, true, false);  VMW(0); BARRIER;   // t=14: drain A15
    att_group(1, false, false); BARRIER;           // t=15

    // collapse att accumulators -> attp (32 regs)
    const int col = n0 + wn * 16 + l15;
    f32x4 attp[8];
    {
        const float ba0 = bias_att[col], ba1 = bias_att[1024 + col];
#pragma unroll
        for (int i = 0; i < 8; ++i)
#pragma unroll
            for (int r = 0; r < 4; ++r)
                attp[i][r] = sigmoidf_(acc2[i][0][r] + ba0) * tanhf_(acc2[i][1][r] + ba1);
    }

    // ================= phase B: gates GEMM, K=2048 (32 tiles of BK=64) =================
    f32x4 acc[8][4];
#pragma unroll
    for (int i = 0; i < 8; ++i)
#pragma unroll
        for (int j = 0; j < 4; ++j) acc[i][j] = z;

    auto gates_group = [&](int buf, bool iss) {
        bf16x8 aF[4][2], bLo[2][2], bHi[2][2];
        // P1: A rf0-3 + B cf0-1 ; MFMA quadrant (rf0-3 x cf0-1)
#pragma unroll
        for (int i = 0; i < 4; ++i) {
            aF[i][0] = ldfrag(&As[buf][aro + i * 1024 + swz0]);
            aF[i][1] = ldfrag(&As[buf][aro + i * 1024 + swz1]);
        }
#pragma unroll
        for (int j = 0; j < 2; ++j) {
            bLo[j][0] = ldfrag(&Bs[buf][brG + j * 1024 + swz0]);
            bLo[j][1] = ldfrag(&Bs[buf][brG + j * 1024 + swz1]);
        }
        BARRIER; LGKM0;
        __builtin_amdgcn_s_setprio(1);
#pragma unroll
        for (int i = 0; i < 4; ++i)
#pragma unroll
            for (int j = 0; j < 2; ++j) {
                acc[i][j] = MFMA16(aF[i][0], bLo[j][0], acc[i][j]);
                acc[i][j] = MFMA16(aF[i][1], bLo[j][1], acc[i][j]);
            }
        __builtin_amdgcn_s_setprio(0);
        BARRIER;
        // P2: B cf2-3 ; MFMA (rf0-3 x cf2-3)
#pragma unroll
        for (int j = 0; j < 2; ++j) {
            bHi[j][0] = ldfrag(&Bs[buf][brG + (2 + j) * 1024 + swz0]);
            bHi[j][1] = ldfrag(&Bs[buf][brG + (2 + j) * 1024 + swz1]);
        }
        BARRIER; LGKM0;
        __builtin_amdgcn_s_setprio(1);
#pragma unroll
        for (int i = 0; i < 4; ++i)
#pragma unroll
            for (int j = 0; j < 2; ++j) {
                acc[i][2 + j] = MFMA16(aF[i][0], bHi[j][0], acc[i][2 + j]);
                acc[i][2 + j] = MFMA16(aF[i][1], bHi[j][1], acc[i][2 + j]);
            }
        __builtin_amdgcn_s_setprio(0);
        BARRIER;
        // P3: A rf4-7 ; issue B(t+2) (B LDS free after P2) ; MFMA (rf4-7 x cf2-3)
#pragma unroll
        for (int i = 0; i < 4; ++i) {
            aF[i][0] = ldfrag(&As[buf][aro + (4 + i) * 1024 + swz0]);
            aF[i][1] = ldfrag(&As[buf][aro + (4 + i) * 1024 + swz1]);
        }
        if (iss) stageB_g(buf);
        BARRIER; LGKM0;
        __builtin_amdgcn_s_setprio(1);
#pragma unroll
        for (int i = 0; i < 4; ++i)
#pragma unroll
            for (int j = 0; j < 2; ++j) {
                acc[4 + i][2 + j] = MFMA16(aF[i][0], bHi[j][0], acc[4 + i][2 + j]);
                acc[4 + i][2 + j] = MFMA16(aF[i][1], bHi[j][1], acc[4 + i][2 + j]);
            }
        __builtin_amdgcn_s_setprio(0);
        BARRIER;
        // P4: issue A(t+2) (A LDS free after P3) ; MFMA (rf4-7 x cf0-1), bLo reused
        if (iss) stageA_g(buf);
        BARRIER;
        __builtin_amdgcn_s_setprio(1);
#pragma unroll
        for (int i = 0; i < 4; ++i)
#pragma unroll
            for (int j = 0; j < 2; ++j) {
                acc[4 + i][j] = MFMA16(aF[i][0], bLo[j][0], acc[4 + i][j]);
                acc[4 + i][j] = MFMA16(aF[i][1], bLo[j][1], acc[4 + i][j]);
            }
        __builtin_amdgcn_s_setprio(0);
    };

    stageA_g(0); stageB_g(0); stageA_g(1); stageB_g(1);   // tiles 0,1
    VMW(8); BARRIER;                                      // tile0 landed; tile1 in flight
#pragma unroll 2
    for (int t = 0; t < 30; ++t) {
        gates_group(t & 1, true);
        VMW(8); BARRIER;                                  // tile t+1 landed; t+2 in flight
    }
    gates_group(0, false); VMW(0); BARRIER;               // t=30: drain tile31
    gates_group(1, false);                                // t=31

    // ---- epilogue: fully in-register LSTM cell ----
    const int Rb = row0 + wr * 128 + quad * 4;
    const float bi  = bias4[col];
    const float bff = bias4[1024 + col];
    const float bg  = bias4[2048 + col];
    const float bo  = bias4[3072 + col];
    const int CYOFF = 8192 * 1024;
#pragma unroll
    for (int i = 0; i < 8; ++i) {
#pragma unroll
        for (int r = 0; r < 4; ++r) {
            const int R   = Rb + i * 16 + r;
            const int off = R * 1024 + col;
            float ig = sigmoidf_(acc[i][0][r] + bi);
            float fg = sigmoidf_(acc[i][1][r] + bff);
            float gg = tanhf_(acc[i][2][r] + bg);
            float og = sigmoidf_(acc[i][3][r] + bo);
            float cyv = fg * cx[off] + ig * gg + attp[i][r];
            float hyv = og * tanhf_(cyv);
            out[off] = hyv;
            out[CYOFF + off] = cyv;
        }
    }
}

// ---------------- launch ----------------
extern "C" void kernel_launch(void* const* d_in, const int* in_sizes, int n_in,
                              void* d_out, int out_size, void* d_ws, size_t ws_size,
                              hipStream_t stream) {
    const float* input = (const float*)d_in[0];
    const float* hx    = (const float*)d_in[1];
    const float* cx    = (const float*)d_in[2];
    const float* att   = (const float*)d_in[3];
    const float* w_ih  = (const float*)d_in[4];
    const float* w_hh  = (const float*)d_in[5];
    const float* b_ih  = (const float*)d_in[6];
    const float* b_hh  = (const float*)d_in[7];
    const float* w_att = (const float*)d_in[8];
    const float* b_att = (const float*)d_in[9];
    float* out = (float*)d_out;

    char* ws = (char*)d_ws;
    unsigned short* XH   = (unsigned short*)(ws);                    // 8192x2048 bf16 (32MB)
    unsigned short* ATTb = (unsigned short*)(ws + 33554432);         // 8192x1024 bf16 (16MB)
    unsigned short* W4   = (unsigned short*)(ws + 50331648);         // 4096x2048 bf16 (16MB)
    unsigned short* WA   = (unsigned short*)(ws + 67108864);         // 2048x1024 bf16 (4MB)
    float* bias4         = (float*)(ws + 71303168);                  // 4096 f32

    cast_all_k<<<8704, 256, 0, stream>>>(input, hx, att, w_ih, w_hh, w_att,
                                         b_ih, b_hh, XH, ATTb, W4, WA, bias4);
    fused_gemm_k<<<512, 512, 0, stream>>>(XH, W4, ATTb, WA, bias4, b_att, cx, out);
}

// Round 2
// 403.390 us; speedup vs baseline: 1.0485x; 1.0485x over previous
//
#include <hip/hip_runtime.h>

// LSTMCell with attention, MI355X gfx950.
// Round 6: fix the round-5 regression.
//  - paired XCD swizzle: block pairs on one XCD share the A row-panel (L2 A-reuse)
//  - gates phases rebalanced 8/8/8/0 reads; stageB at P3, stageA at P4 (both
//    target regions proven quiescent by the preceding barrier -> no LDS WAR race)
//  - att processed as tile-pairs (buf0/buf1), 10/10 reads, stages only into
//    quiescent buffers, counted VMW(6)
//  - epilogue fully coalesced via LDS: fg/cyP/og staged in the 128KB LDS, cx read
//    and hy/cy written as 256B row segments (kills RFO + 2x cx amplification)

typedef __attribute__((ext_vector_type(8))) __bf16 bf16x8;
typedef __attribute__((ext_vector_type(8))) unsigned short ushort8;
typedef __attribute__((ext_vector_type(4))) float f32x4;

#define AS1 __attribute__((address_space(1)))
#define AS3 __attribute__((address_space(3)))

__device__ __forceinline__ void gld16(const unsigned short* g, unsigned short* l) {
    __builtin_amdgcn_global_load_lds((const AS1 void*)g, (AS3 void*)l, 16, 0, 0);
}

__device__ __forceinline__ unsigned short f2bf(float f) {
    unsigned int u = __builtin_bit_cast(unsigned int, f);
    u += 0x7fffu + ((u >> 16) & 1u);   // RNE
    return (unsigned short)(u >> 16);
}

__device__ __forceinline__ float sigmoidf_(float x) { return 1.f / (1.f + __expf(-x)); }
__device__ __forceinline__ float tanhf_(float x) {
    float e = __expf(-2.f * fabsf(x));
    float t = (1.f - e) / (1.f + e);
    return x >= 0.f ? t : -t;
}

__device__ __forceinline__ bf16x8 ldfrag(const unsigned short* p) {
    return __builtin_bit_cast(bf16x8, *(const ushort8*)p);
}

#define BARRIER __builtin_amdgcn_s_barrier()
#define LGKM0   asm volatile("s_waitcnt lgkmcnt(0)" ::: "memory")
#define VMW_(n) asm volatile("s_waitcnt vmcnt(" #n ")" ::: "memory")
#define VMW(n)  VMW_(n)
#define PRIO1   __builtin_amdgcn_s_setprio(1)
#define PRIO0   __builtin_amdgcn_s_setprio(0)
#define MFMA16(a, b, c) __builtin_amdgcn_mfma_f32_16x16x32_bf16(a, b, c, 0, 0, 0)

// ---------------- fused cast/pack + bias kernel (BW-bound, ~33us) ----------------
__global__ void cast_all_k(const float* __restrict__ input, const float* __restrict__ hx,
                           const float* __restrict__ att,   const float* __restrict__ w_ih,
                           const float* __restrict__ w_hh,  const float* __restrict__ w_att,
                           const float* __restrict__ b_ih,  const float* __restrict__ b_hh,
                           unsigned short* __restrict__ XH, unsigned short* __restrict__ ATTb,
                           unsigned short* __restrict__ W4, unsigned short* __restrict__ WA,
                           float* __restrict__ bias4)
{
    int gid = blockIdx.x * blockDim.x + threadIdx.x;
    if (gid < 4096) bias4[gid] = b_ih[gid] + b_hh[gid];
    const int total = 4456448;  // total float8 units
    for (int i = gid; i < total; i += gridDim.x * blockDim.x) {
        const float* src; unsigned short* dst; int ld, off, rel;
        if (i < 1048576)      { src = input; dst = XH;   ld = 2048; off = 0;    rel = i; }
        else if (i < 2097152) { src = hx;    dst = XH;   ld = 2048; off = 1024; rel = i - 1048576; }
        else if (i < 3145728) { src = att;   dst = ATTb; ld = 1024; off = 0;    rel = i - 2097152; }
        else if (i < 3670016) { src = w_ih;  dst = W4;   ld = 2048; off = 0;    rel = i - 3145728; }
        else if (i < 4194304) { src = w_hh;  dst = W4;   ld = 2048; off = 1024; rel = i - 3670016; }
        else                  { src = w_att; dst = WA;   ld = 1024; off = 0;    rel = i - 4194304; }
        int e = rel * 8;
        int r = e >> 10, c = e & 1023;   // all sources have 1024 fp32 cols
        const float4 v0 = *(const float4*)(src + e);
        const float4 v1 = *(const float4*)(src + e + 4);
        ushort8 p;
        p[0] = f2bf(v0.x); p[1] = f2bf(v0.y); p[2] = f2bf(v0.z); p[3] = f2bf(v0.w);
        p[4] = f2bf(v1.x); p[5] = f2bf(v1.y); p[6] = f2bf(v1.z); p[7] = f2bf(v1.w);
        *(ushort8*)(dst + r * ld + off + c) = p;
    }
}

// ---------------- fused GEMM + full LSTM epilogue ----------------
__global__ __launch_bounds__(512, 2) void fused_gemm_k(
    const unsigned short* __restrict__ XH, const unsigned short* __restrict__ W4,
    const unsigned short* __restrict__ ATTb, const unsigned short* __restrict__ WA,
    const float* __restrict__ bias4, const float* __restrict__ bias_att,
    const float* __restrict__ cx, float* __restrict__ out)
{
    __shared__ unsigned short As[2][16384];   // 2 x 32KB
    __shared__ unsigned short Bs[2][16384];   // 2 x 32KB

    const int tid  = threadIdx.x;
    const int wave = tid >> 6, lane = tid & 63;
    const int l15 = lane & 15, quad = lane >> 4;
    const int wr = wave >> 2, wn = wave & 3;

    // paired XCD swizzle: XCD = orig&7; consecutive k share a row-panel so the
    // two CUs pull the same A tiles (L2 hit for the second), cols stay per-XCD.
    const int orig = blockIdx.x;
    const int k    = orig >> 3, xcd = orig & 7;
    const int row0 = (k >> 1) * 256;             // 32 row panels
    const int n0   = (xcd * 2 + (k & 1)) * 64;   // 16 col panels

    // ---- staging geometry: thread t stages LDS chunk (tid + p*512) of each half
    const int rl = tid >> 3;                         // 0..63
    const int c8 = (tid & 7) ^ (rl & 7);             // source k-chunk (swizzled)
    unsigned aG = (unsigned)(row0 + rl) * 2048u + (unsigned)c8 * 8u;
    unsigned bG = (unsigned)(((rl >> 4) & 3) * 1024 + n0 + (rl & 15)) * 2048u + (unsigned)c8 * 8u;
    unsigned aA = (unsigned)(row0 + rl) * 1024u + (unsigned)c8 * 8u;
    unsigned bA = (unsigned)(((rl >> 4) & 1) * 1024 + n0 + ((rl >> 5) & 1) * 16 + (rl & 15)) * 1024u
                  + (unsigned)c8 * 8u;

    auto stageA_att = [&](int buf) {   // 4 loads: 256x64 A tile
#pragma unroll
        for (int h = 0; h < 2; ++h)
#pragma unroll
            for (int p = 0; p < 2; ++p)
                gld16(ATTb + aA + (unsigned)(h * 131072 + p * 65536),
                      &As[buf][h * 8192 + (tid + p * 512) * 8]);
        aA += 64;
    };
    auto stageB_att = [&](int buf) {   // 2 loads: 128x64 B tile
#pragma unroll
        for (int h = 0; h < 2; ++h)
            gld16(WA + bA + (unsigned)(h * 32768), &Bs[buf][(h * 512 + tid) * 8]);
        bA += 64;
    };
    auto stageA_g = [&](int buf) {     // 4 loads: 256x64 A tile
#pragma unroll
        for (int h = 0; h < 2; ++h)
#pragma unroll
            for (int p = 0; p < 2; ++p)
                gld16(XH + aG + (unsigned)(h * 262144 + p * 131072),
                      &As[buf][h * 8192 + (tid + p * 512) * 8]);
        aG += 64;
    };
    auto stageB_g = [&](int buf) {     // 4 loads: 256x64 B tile
#pragma unroll
        for (int h = 0; h < 2; ++h)
#pragma unroll
            for (int p = 0; p < 2; ++p)
                gld16(W4 + bG + (unsigned)(h * 65536 + p * 32768),
                      &Bs[buf][h * 8192 + (tid + p * 512) * 8]);
        bG += 64;
    };

    // fragment read constants (lane-local)
    const int swz0 = (quad ^ (l15 & 7)) * 8;
    const int swz1 = ((4 + quad) ^ (l15 & 7)) * 8;
    const int aro  = (wr * 128 + l15) * 64;
    const int brG  = (wn * 64 + l15) * 64;
    const int brA  = (wn * 32 + l15) * 64;

    const f32x4 z = {0.f, 0.f, 0.f, 0.f};

    // ================= phase A: att GEMM, K=1024 (8 pairs of BK=64 tiles) =========
    f32x4 acc2[8][2];
#pragma unroll
    for (int i = 0; i < 8; ++i) { acc2[i][0] = z; acc2[i][1] = z; }

    auto att_slice = [&](int buf, int sw) {   // reads + 16 MFMA for one k-slice
        bf16x8 aS[8], bS[2];
#pragma unroll
        for (int i = 0; i < 8; ++i) aS[i] = ldfrag(&As[buf][aro + i * 1024 + sw]);
#pragma unroll
        for (int j = 0; j < 2; ++j) bS[j] = ldfrag(&Bs[buf][brA + j * 1024 + sw]);
        BARRIER; LGKM0;
        PRIO1;
#pragma unroll
        for (int i = 0; i < 8; ++i)
#pragma unroll
            for (int j = 0; j < 2; ++j)
                acc2[i][j] = MFMA16(aS[i], bS[j], acc2[i][j]);
        PRIO0;
        BARRIER;
    };

    stageA_att(0); stageB_att(0);            // tile0 -> buf0
    for (int g = 0; g < 8; ++g) {
        // P1: stage odd tile (2g+1) -> buf1 (quiescent since prev P4 barrier)
        stageA_att(1); stageB_att(1);
        VMW(6); BARRIER;                     // even tile landed everywhere
        att_slice(0, swz0);                  // P1 MFMA
        att_slice(0, swz1);                  // P2 (buf0 fully read at its barrier)
        // P3: stage next even tile (2g+2) -> buf0
        if (g < 7) { stageA_att(0); stageB_att(0); VMW(6); }
        else       { VMW(0); }
        BARRIER;                             // odd tile landed everywhere
        att_slice(1, swz0);                  // P3 MFMA
        att_slice(1, swz1);                  // P4 (buf1 quiescent for next g)
    }

    // collapse att accumulators -> attp (32 regs)
    const int col = n0 + wn * 16 + l15;
    f32x4 attp[8];
    {
        const float ba0 = bias_att[col], ba1 = bias_att[1024 + col];
#pragma unroll
        for (int i = 0; i < 8; ++i)
#pragma unroll
            for (int r = 0; r < 4; ++r)
                attp[i][r] = sigmoidf_(acc2[i][0][r] + ba0) * tanhf_(acc2[i][1][r] + ba1);
    }

    // ================= phase B: gates GEMM, K=2048 (32 tiles of BK=64) =============
    f32x4 acc[8][4];
#pragma unroll
    for (int i = 0; i < 8; ++i)
#pragma unroll
        for (int j = 0; j < 4; ++j) acc[i][j] = z;

    auto gates_group = [&](int buf, bool iss) {
        bf16x8 aF[4], aH0[4], aH1[4], bS0[4], bS1[4];
        // P1: aLo_s0(4) + bAll_s0(4); MFMA rf0-3 x cf0-3 x s0
#pragma unroll
        for (int i = 0; i < 4; ++i) aF[i] = ldfrag(&As[buf][aro + i * 1024 + swz0]);
#pragma unroll
        for (int j = 0; j < 4; ++j) bS0[j] = ldfrag(&Bs[buf][brG + j * 1024 + swz0]);
        BARRIER; LGKM0;
        PRIO1;
#pragma unroll
        for (int i = 0; i < 4; ++i)
#pragma unroll
            for (int j = 0; j < 4; ++j)
                acc[i][j] = MFMA16(aF[i], bS0[j], acc[i][j]);
        PRIO0;
        BARRIER;
        // P2: aLo_s1(4) + bAll_s1(4); MFMA rf0-3 x s1  (B region fully read after)
#pragma unroll
        for (int i = 0; i < 4; ++i) aF[i] = ldfrag(&As[buf][aro + i * 1024 + swz1]);
#pragma unroll
        for (int j = 0; j < 4; ++j) bS1[j] = ldfrag(&Bs[buf][brG + j * 1024 + swz1]);
        BARRIER; LGKM0;
        PRIO1;
#pragma unroll
        for (int i = 0; i < 4; ++i)
#pragma unroll
            for (int j = 0; j < 4; ++j)
                acc[i][j] = MFMA16(aF[i], bS1[j], acc[i][j]);
        PRIO0;
        BARRIER;
        // P3: aHi both s (8); stageB(t+2) -> B quiescent; MFMA rf4-7 x s0
#pragma unroll
        for (int i = 0; i < 4; ++i) {
            aH0[i] = ldfrag(&As[buf][aro + (4 + i) * 1024 + swz0]);
            aH1[i] = ldfrag(&As[buf][aro + (4 + i) * 1024 + swz1]);
        }
        if (iss) stageB_g(buf);
        BARRIER; LGKM0;
        PRIO1;
#pragma unroll
        for (int i = 0; i < 4; ++i)
#pragma unroll
            for (int j = 0; j < 4; ++j)
                acc[4 + i][j] = MFMA16(aH0[i], bS0[j], acc[4 + i][j]);
        PRIO0;
        BARRIER;
        // P4: stageA(t+2) -> A quiescent after P3 barrier; pure MFMA rf4-7 x s1
        if (iss) stageA_g(buf);
        PRIO1;
#pragma unroll
        for (int i = 0; i < 4; ++i)
#pragma unroll
            for (int j = 0; j < 4; ++j)
                acc[4 + i][j] = MFMA16(aH1[i], bS1[j], acc[4 + i][j]);
        PRIO0;
    };

    stageA_g(0); stageB_g(0); stageA_g(1); stageB_g(1);   // tiles 0,1
    VMW(8); BARRIER;                                      // tile0 landed; tile1 in flight
#pragma unroll 2
    for (int t = 0; t < 30; ++t) {
        gates_group(t & 1, true);
        VMW(8); BARRIER;                                  // tile t+1 landed; t+2 in flight
    }
    gates_group(0, false); VMW(0); BARRIER;               // drain tile31
    gates_group(1, false);

    // ---- epilogue: LSTM cell, coalesced via LDS ----
    // LDS reuse: sF (As, 64KB) holds fg then cy; sC (Bs, 64KB) holds cyP then og.
    float* sF = (float*)(&As[0][0]);
    float* sC = (float*)(&Bs[0][0]);
    const float bi  = bias4[col];
    const float bff = bias4[1024 + col];
    const float bg  = bias4[2048 + col];
    const float bo  = bias4[3072 + col];
    const int lcol  = wn * 16 + l15;
    const int CYOFF = 8192 * 1024;

    // step1: per-thread layout -> LDS (fg, cyP); col XOR'd by row bit2 (2-way banks)
#pragma unroll
    for (int i = 0; i < 8; ++i)
#pragma unroll
        for (int r = 0; r < 4; ++r) {
            const int lr = wr * 128 + i * 16 + quad * 4 + r;
            const int pc = lcol ^ (((lr >> 2) & 1) << 4);
            sF[lr * 64 + pc] = sigmoidf_(acc[i][1][r] + bff);
            sC[lr * 64 + pc] = sigmoidf_(acc[i][0][r] + bi) * tanhf_(acc[i][2][r] + bg)
                               + attp[i][r];
        }
    BARRIER;

    // step2: coalesced cy = fg*cx + cyP; write cy back into sF
    const int rr = tid >> 4;              // 0..31
    const int cc = (tid & 15) * 4;        // 0..60
#pragma unroll
    for (int p = 0; p < 8; ++p) {
        const int row = p * 32 + rr;
        const int pcc = cc ^ (((row >> 2) & 1) << 4);
        f32x4 fg4 = *(f32x4*)&sF[row * 64 + pcc];
        f32x4 cp4 = *(f32x4*)&sC[row * 64 + pcc];
        const float4 cx4 = *(const float4*)&cx[(row0 + row) * 1024 + n0 + cc];
        f32x4 cy4;
        cy4[0] = fg4[0] * cx4.x + cp4[0];
        cy4[1] = fg4[1] * cx4.y + cp4[1];
        cy4[2] = fg4[2] * cx4.z + cp4[2];
        cy4[3] = fg4[3] * cx4.w + cp4[3];
        *(f32x4*)&out[CYOFF + (row0 + row) * 1024 + n0 + cc] = cy4;
        *(f32x4*)&sF[row * 64 + pcc] = cy4;
    }
    BARRIER;

    // step3: per-thread og -> sC (cyP slots dead)
#pragma unroll
    for (int i = 0; i < 8; ++i)
#pragma unroll
        for (int r = 0; r < 4; ++r) {
            const int lr = wr * 128 + i * 16 + quad * 4 + r;
            const int pc = lcol ^ (((lr >> 2) & 1) << 4);
            sC[lr * 64 + pc] = sigmoidf_(acc[i][3][r] + bo);
        }
    BARRIER;

    // step4: coalesced hy = og * tanh(cy)
#pragma unroll
    for (int p = 0; p < 8; ++p) {
        const int row = p * 32 + rr;
        const int pcc = cc ^ (((row >> 2) & 1) << 4);
        f32x4 og4 = *(f32x4*)&sC[row * 64 + pcc];
        f32x4 cy4 = *(f32x4*)&sF[row * 64 + pcc];
        f32x4 hy4;
        hy4[0] = og4[0] * tanhf_(cy4[0]);
        hy4[1] = og4[1] * tanhf_(cy4[1]);
        hy4[2] = og4[2] * tanhf_(cy4[2]);
        hy4[3] = og4[3] * tanhf_(cy4[3]);
        *(f32x4*)&out[(row0 + row) * 1024 + n0 + cc] = hy4;
    }
}

// ---------------- launch ----------------
extern "C" void kernel_launch(void* const* d_in, const int* in_sizes, int n_in,
                              void* d_out, int out_size, void* d_ws, size_t ws_size,
                              hipStream_t stream) {
    const float* input = (const float*)d_in[0];
    const float* hx    = (const float*)d_in[1];
    const float* cx    = (const float*)d_in[2];
    const float* att   = (const float*)d_in[3];
    const float* w_ih  = (const float*)d_in[4];
    const float* w_hh  = (const float*)d_in[5];
    const float* b_ih  = (const float*)d_in[6];
    const float* b_hh  = (const float*)d_in[7];
    const float* w_att = (const float*)d_in[8];
    const float* b_att = (const float*)d_in[9];
    float* out = (float*)d_out;

    char* ws = (char*)d_ws;
    unsigned short* XH   = (unsigned short*)(ws);                    // 8192x2048 bf16 (32MB)
    unsigned short* ATTb = (unsigned short*)(ws + 33554432);         // 8192x1024 bf16 (16MB)
    unsigned short* W4   = (unsigned short*)(ws + 50331648);         // 4096x2048 bf16 (16MB)
    unsigned short* WA   = (unsigned short*)(ws + 67108864);         // 2048x1024 bf16 (4MB)
    float* bias4         = (float*)(ws + 71303168);                  // 4096 f32

    cast_all_k<<<8704, 256, 0, stream>>>(input, hx, att, w_ih, w_hh, w_att,
                                         b_ih, b_hh, XH, ATTb, W4, WA, bias4);
    fused_gemm_k<<<512, 512, 0, stream>>>(XH, W4, ATTb, WA, bias4, b_att, cx, out);
}

// Round 3
// 401.649 us; speedup vs baseline: 1.0530x; 1.0043x over previous
//
#include <hip/hip_runtime.h>

// LSTMCell with attention, MI355X gfx950.
// Round 7: de-confound R5/R6.
//  - gates_group restored to the m201 quadrant order (12/4/8/0 reads; bLo live
//    P1->P4; aF live P1->P2) -- the proven 62%-MfmaUtil rhythm
//  - R4C8 concurrency swizzle: each XCD owns 4 row-panels x 16 col-panels; the
//    32 concurrent blocks = 4 rows x 8 cols -> 12 L3 fill-streams/XCD (was 18),
//    8-way L2 A-reuse (was 2-way)
//  - barrier before epilogue LDS reuse (latent race)
//  - epilogue stays LDS-coalesced (R6), att phase stays tile-paired (R6)

typedef __attribute__((ext_vector_type(8))) __bf16 bf16x8;
typedef __attribute__((ext_vector_type(8))) unsigned short ushort8;
typedef __attribute__((ext_vector_type(4))) float f32x4;

#define AS1 __attribute__((address_space(1)))
#define AS3 __attribute__((address_space(3)))

__device__ __forceinline__ void gld16(const unsigned short* g, unsigned short* l) {
    __builtin_amdgcn_global_load_lds((const AS1 void*)g, (AS3 void*)l, 16, 0, 0);
}

__device__ __forceinline__ unsigned short f2bf(float f) {
    unsigned int u = __builtin_bit_cast(unsigned int, f);
    u += 0x7fffu + ((u >> 16) & 1u);   // RNE
    return (unsigned short)(u >> 16);
}

__device__ __forceinline__ float sigmoidf_(float x) { return 1.f / (1.f + __expf(-x)); }
__device__ __forceinline__ float tanhf_(float x) {
    float e = __expf(-2.f * fabsf(x));
    float t = (1.f - e) / (1.f + e);
    return x >= 0.f ? t : -t;
}

__device__ __forceinline__ bf16x8 ldfrag(const unsigned short* p) {
    return __builtin_bit_cast(bf16x8, *(const ushort8*)p);
}

#define BARRIER __builtin_amdgcn_s_barrier()
#define LGKM0   asm volatile("s_waitcnt lgkmcnt(0)" ::: "memory")
#define VMW_(n) asm volatile("s_waitcnt vmcnt(" #n ")" ::: "memory")
#define VMW(n)  VMW_(n)
#define PRIO1   __builtin_amdgcn_s_setprio(1)
#define PRIO0   __builtin_amdgcn_s_setprio(0)
#define MFMA16(a, b, c) __builtin_amdgcn_mfma_f32_16x16x32_bf16(a, b, c, 0, 0, 0)

// ---------------- fused cast/pack + bias kernel (BW-bound, ~33us) ----------------
__global__ void cast_all_k(const float* __restrict__ input, const float* __restrict__ hx,
                           const float* __restrict__ att,   const float* __restrict__ w_ih,
                           const float* __restrict__ w_hh,  const float* __restrict__ w_att,
                           const float* __restrict__ b_ih,  const float* __restrict__ b_hh,
                           unsigned short* __restrict__ XH, unsigned short* __restrict__ ATTb,
                           unsigned short* __restrict__ W4, unsigned short* __restrict__ WA,
                           float* __restrict__ bias4)
{
    int gid = blockIdx.x * blockDim.x + threadIdx.x;
    if (gid < 4096) bias4[gid] = b_ih[gid] + b_hh[gid];
    const int total = 4456448;  // total float8 units
    for (int i = gid; i < total; i += gridDim.x * blockDim.x) {
        const float* src; unsigned short* dst; int ld, off, rel;
        if (i < 1048576)      { src = input; dst = XH;   ld = 2048; off = 0;    rel = i; }
        else if (i < 2097152) { src = hx;    dst = XH;   ld = 2048; off = 1024; rel = i - 1048576; }
        else if (i < 3145728) { src = att;   dst = ATTb; ld = 1024; off = 0;    rel = i - 2097152; }
        else if (i < 3670016) { src = w_ih;  dst = W4;   ld = 2048; off = 0;    rel = i - 3145728; }
        else if (i < 4194304) { src = w_hh;  dst = W4;   ld = 2048; off = 1024; rel = i - 3670016; }
        else                  { src = w_att; dst = WA;   ld = 1024; off = 0;    rel = i - 4194304; }
        int e = rel * 8;
        int r = e >> 10, c = e & 1023;   // all sources have 1024 fp32 cols
        const float4 v0 = *(const float4*)(src + e);
        const float4 v1 = *(const float4*)(src + e + 4);
        ushort8 p;
        p[0] = f2bf(v0.x); p[1] = f2bf(v0.y); p[2] = f2bf(v0.z); p[3] = f2bf(v0.w);
        p[4] = f2bf(v1.x); p[5] = f2bf(v1.y); p[6] = f2bf(v1.z); p[7] = f2bf(v1.w);
        *(ushort8*)(dst + r * ld + off + c) = p;
    }
}

// ---------------- fused GEMM + full LSTM epilogue ----------------
__global__ __launch_bounds__(512, 2) void fused_gemm_k(
    const unsigned short* __restrict__ XH, const unsigned short* __restrict__ W4,
    const unsigned short* __restrict__ ATTb, const unsigned short* __restrict__ WA,
    const float* __restrict__ bias4, const float* __restrict__ bias_att,
    const float* __restrict__ cx, float* __restrict__ out)
{
    __shared__ unsigned short As[2][16384];   // 2 x 32KB
    __shared__ unsigned short Bs[2][16384];   // 2 x 32KB

    const int tid  = threadIdx.x;
    const int wave = tid >> 6, lane = tid & 63;
    const int l15 = lane & 15, quad = lane >> 4;
    const int wr = wave >> 2, wn = wave & 3;

    // R4C8 swizzle: XCD = orig&7 owns row panels xcd*4..xcd*4+3 across all 16
    // col panels. Concurrent 32 blocks/XCD = 4 row panels x 8 col panels ->
    // 12 L3 fill streams (4 A + 8 B), 8-way L2 A-reuse.
    const int orig  = blockIdx.x;
    const int xcd   = orig & 7, local = orig >> 3;
    const int row0  = (xcd * 4 + (local & 3)) * 256;   // 32 row panels
    const int n0    = (local >> 2) * 64;               // 16 col panels

    // ---- staging geometry: thread t stages LDS chunk (tid + p*512) of each half
    const int rl = tid >> 3;                         // 0..63
    const int c8 = (tid & 7) ^ (rl & 7);             // source k-chunk (swizzled)
    unsigned aG = (unsigned)(row0 + rl) * 2048u + (unsigned)c8 * 8u;
    unsigned bG = (unsigned)(((rl >> 4) & 3) * 1024 + n0 + (rl & 15)) * 2048u + (unsigned)c8 * 8u;
    unsigned aA = (unsigned)(row0 + rl) * 1024u + (unsigned)c8 * 8u;
    unsigned bA = (unsigned)(((rl >> 4) & 1) * 1024 + n0 + ((rl >> 5) & 1) * 16 + (rl & 15)) * 1024u
                  + (unsigned)c8 * 8u;

    auto stageA_att = [&](int buf) {   // 4 loads: 256x64 A tile
#pragma unroll
        for (int h = 0; h < 2; ++h)
#pragma unroll
            for (int p = 0; p < 2; ++p)
                gld16(ATTb + aA + (unsigned)(h * 131072 + p * 65536),
                      &As[buf][h * 8192 + (tid + p * 512) * 8]);
        aA += 64;
    };
    auto stageB_att = [&](int buf) {   // 2 loads: 128x64 B tile
#pragma unroll
        for (int h = 0; h < 2; ++h)
            gld16(WA + bA + (unsigned)(h * 32768), &Bs[buf][(h * 512 + tid) * 8]);
        bA += 64;
    };
    auto stageA_g = [&](int buf) {     // 4 loads: 256x64 A tile
#pragma unroll
        for (int h = 0; h < 2; ++h)
#pragma unroll
            for (int p = 0; p < 2; ++p)
                gld16(XH + aG + (unsigned)(h * 262144 + p * 131072),
                      &As[buf][h * 8192 + (tid + p * 512) * 8]);
        aG += 64;
    };
    auto stageB_g = [&](int buf) {     // 4 loads: 256x64 B tile
#pragma unroll
        for (int h = 0; h < 2; ++h)
#pragma unroll
            for (int p = 0; p < 2; ++p)
                gld16(W4 + bG + (unsigned)(h * 65536 + p * 32768),
                      &Bs[buf][h * 8192 + (tid + p * 512) * 8]);
        bG += 64;
    };

    // fragment read constants (lane-local)
    const int swz0 = (quad ^ (l15 & 7)) * 8;
    const int swz1 = ((4 + quad) ^ (l15 & 7)) * 8;
    const int aro  = (wr * 128 + l15) * 64;
    const int brG  = (wn * 64 + l15) * 64;
    const int brA  = (wn * 32 + l15) * 64;

    const f32x4 z = {0.f, 0.f, 0.f, 0.f};

    // ================= phase A: att GEMM, K=1024 (8 pairs of BK=64 tiles) =========
    f32x4 acc2[8][2];
#pragma unroll
    for (int i = 0; i < 8; ++i) { acc2[i][0] = z; acc2[i][1] = z; }

    auto att_slice = [&](int buf, int sw) {   // reads + 16 MFMA for one k-slice
        bf16x8 aS[8], bS[2];
#pragma unroll
        for (int i = 0; i < 8; ++i) aS[i] = ldfrag(&As[buf][aro + i * 1024 + sw]);
#pragma unroll
        for (int j = 0; j < 2; ++j) bS[j] = ldfrag(&Bs[buf][brA + j * 1024 + sw]);
        BARRIER; LGKM0;
        PRIO1;
#pragma unroll
        for (int i = 0; i < 8; ++i)
#pragma unroll
            for (int j = 0; j < 2; ++j)
                acc2[i][j] = MFMA16(aS[i], bS[j], acc2[i][j]);
        PRIO0;
        BARRIER;
    };

    stageA_att(0); stageB_att(0);            // tile0 -> buf0
    for (int g = 0; g < 8; ++g) {
        // stage odd tile (2g+1) -> buf1 (quiescent since prev pair's last barrier)
        stageA_att(1); stageB_att(1);
        VMW(6); BARRIER;                     // even tile landed everywhere
        att_slice(0, swz0);
        att_slice(0, swz1);                  // buf0 fully read at its barrier
        // stage next even tile (2g+2) -> buf0
        if (g < 7) { stageA_att(0); stageB_att(0); VMW(6); }
        else       { VMW(0); }
        BARRIER;                             // odd tile landed everywhere
        att_slice(1, swz0);
        att_slice(1, swz1);                  // buf1 quiescent for next g
    }

    // collapse att accumulators -> attp (32 regs)
    const int col = n0 + wn * 16 + l15;
    f32x4 attp[8];
    {
        const float ba0 = bias_att[col], ba1 = bias_att[1024 + col];
#pragma unroll
        for (int i = 0; i < 8; ++i)
#pragma unroll
            for (int r = 0; r < 4; ++r)
                attp[i][r] = sigmoidf_(acc2[i][0][r] + ba0) * tanhf_(acc2[i][1][r] + ba1);
    }

    // ================= phase B: gates GEMM, K=2048 (32 tiles of BK=64) =============
    f32x4 acc[8][4];
#pragma unroll
    for (int i = 0; i < 8; ++i)
#pragma unroll
        for (int j = 0; j < 4; ++j) acc[i][j] = z;

    // m201 quadrant order: P1 rf0-3 x cf0-1 (12 reads), P2 rf0-3 x cf2-3 (4),
    // P3 rf4-7 x cf2-3 (8, stageB), P4 rf4-7 x cf0-1 (0, stageA; bLo reused).
    auto gates_group = [&](int buf, bool iss) {
        bf16x8 aF0[4], aF1[4], aH0[4], aH1[4], bL0[2], bL1[2], bH0[2], bH1[2];
        // P1
#pragma unroll
        for (int i = 0; i < 4; ++i) {
            aF0[i] = ldfrag(&As[buf][aro + i * 1024 + swz0]);
            aF1[i] = ldfrag(&As[buf][aro + i * 1024 + swz1]);
        }
#pragma unroll
        for (int j = 0; j < 2; ++j) {
            bL0[j] = ldfrag(&Bs[buf][brG + j * 1024 + swz0]);
            bL1[j] = ldfrag(&Bs[buf][brG + j * 1024 + swz1]);
        }
        BARRIER; LGKM0;
        PRIO1;
#pragma unroll
        for (int i = 0; i < 4; ++i)
#pragma unroll
            for (int j = 0; j < 2; ++j) {
                acc[i][j] = MFMA16(aF0[i], bL0[j], acc[i][j]);
                acc[i][j] = MFMA16(aF1[i], bL1[j], acc[i][j]);
            }
        PRIO0;
        BARRIER;
        // P2
#pragma unroll
        for (int j = 0; j < 2; ++j) {
            bH0[j] = ldfrag(&Bs[buf][brG + (2 + j) * 1024 + swz0]);
            bH1[j] = ldfrag(&Bs[buf][brG + (2 + j) * 1024 + swz1]);
        }
        BARRIER; LGKM0;
        PRIO1;
#pragma unroll
        for (int i = 0; i < 4; ++i)
#pragma unroll
            for (int j = 0; j < 2; ++j) {
                acc[i][2 + j] = MFMA16(aF0[i], bH0[j], acc[i][2 + j]);
                acc[i][2 + j] = MFMA16(aF1[i], bH1[j], acc[i][2 + j]);
            }
        PRIO0;
        BARRIER;
        // P3 (B region fully read after P2's barrier -> stageB safe)
#pragma unroll
        for (int i = 0; i < 4; ++i) {
            aH0[i] = ldfrag(&As[buf][aro + (4 + i) * 1024 + swz0]);
            aH1[i] = ldfrag(&As[buf][aro + (4 + i) * 1024 + swz1]);
        }
        if (iss) stageB_g(buf);
        BARRIER; LGKM0;
        PRIO1;
#pragma unroll
        for (int i = 0; i < 4; ++i)
#pragma unroll
            for (int j = 0; j < 2; ++j) {
                acc[4 + i][2 + j] = MFMA16(aH0[i], bH0[j], acc[4 + i][2 + j]);
                acc[4 + i][2 + j] = MFMA16(aH1[i], bH1[j], acc[4 + i][2 + j]);
            }
        PRIO0;
        BARRIER;
        // P4 (A region fully read after P3's barrier -> stageA safe); pure MFMA
        if (iss) stageA_g(buf);
        PRIO1;
#pragma unroll
        for (int i = 0; i < 4; ++i)
#pragma unroll
            for (int j = 0; j < 2; ++j) {
                acc[4 + i][j] = MFMA16(aH0[i], bL0[j], acc[4 + i][j]);
                acc[4 + i][j] = MFMA16(aH1[i], bL1[j], acc[4 + i][j]);
            }
        PRIO0;
    };

    stageA_g(0); stageB_g(0); stageA_g(1); stageB_g(1);   // tiles 0,1
    VMW(8); BARRIER;                                      // tile0 landed; tile1 in flight
#pragma unroll 2
    for (int t = 0; t < 30; ++t) {
        gates_group(t & 1, true);
        VMW(8); BARRIER;                                  // tile t+1 landed; t+2 in flight
    }
    gates_group(0, false); VMW(0); BARRIER;               // drain tile31
    gates_group(1, false);
    BARRIER;                                              // all LDS reads done before reuse

    // ---- epilogue: LSTM cell, coalesced via LDS ----
    // LDS reuse: sF (As, 64KB) holds fg then cy; sC (Bs, 64KB) holds cyP then og.
    float* sF = (float*)(&As[0][0]);
    float* sC = (float*)(&Bs[0][0]);
    const float bi  = bias4[col];
    const float bff = bias4[1024 + col];
    const float bg  = bias4[2048 + col];
    const float bo  = bias4[3072 + col];
    const int lcol  = wn * 16 + l15;
    const int CYOFF = 8192 * 1024;

    // step1: per-thread layout -> LDS (fg, cyP); col XOR'd by row bit2 (2-way banks)
#pragma unroll
    for (int i = 0; i < 8; ++i)
#pragma unroll
        for (int r = 0; r < 4; ++r) {
            const int lr = wr * 128 + i * 16 + quad * 4 + r;
            const int pc = lcol ^ (((lr >> 2) & 1) << 4);
            sF[lr * 64 + pc] = sigmoidf_(acc[i][1][r] + bff);
            sC[lr * 64 + pc] = sigmoidf_(acc[i][0][r] + bi) * tanhf_(acc[i][2][r] + bg)
                               + attp[i][r];
        }
    BARRIER;

    // step2: coalesced cy = fg*cx + cyP; write cy back into sF
    const int rr = tid >> 4;              // 0..31
    const int cc = (tid & 15) * 4;        // 0..60
#pragma unroll
    for (int p = 0; p < 8; ++p) {
        const int row = p * 32 + rr;
        const int pcc = cc ^ (((row >> 2) & 1) << 4);
        f32x4 fg4 = *(f32x4*)&sF[row * 64 + pcc];
        f32x4 cp4 = *(f32x4*)&sC[row * 64 + pcc];
        const float4 cx4 = *(const float4*)&cx[(row0 + row) * 1024 + n0 + cc];
        f32x4 cy4;
        cy4[0] = fg4[0] * cx4.x + cp4[0];
        cy4[1] = fg4[1] * cx4.y + cp4[1];
        cy4[2] = fg4[2] * cx4.z + cp4[2];
        cy4[3] = fg4[3] * cx4.w + cp4[3];
        *(f32x4*)&out[CYOFF + (row0 + row) * 1024 + n0 + cc] = cy4;
        *(f32x4*)&sF[row * 64 + pcc] = cy4;
    }
    BARRIER;

    // step3: per-thread og -> sC (cyP slots dead)
#pragma unroll
    for (int i = 0; i < 8; ++i)
#pragma unroll
        for (int r = 0; r < 4; ++r) {
            const int lr = wr * 128 + i * 16 + quad * 4 + r;
            const int pc = lcol ^ (((lr >> 2) & 1) << 4);
            sC[lr * 64 + pc] = sigmoidf_(acc[i][3][r] + bo);
        }
    BARRIER;

    // step4: coalesced hy = og * tanh(cy)
#pragma unroll
    for (int p = 0; p < 8; ++p) {
        const int row = p * 32 + rr;
        const int pcc = cc ^ (((row >> 2) & 1) << 4);
        f32x4 og4 = *(f32x4*)&sC[row * 64 + pcc];
        f32x4 cy4 = *(f32x4*)&sF[row * 64 + pcc];
        f32x4 hy4;
        hy4[0] = og4[0] * tanhf_(cy4[0]);
        hy4[1] = og4[1] * tanhf_(cy4[1]);
        hy4[2] = og4[2] * tanhf_(cy4[2]);
        hy4[3] = og4[3] * tanhf_(cy4[3]);
        *(f32x4*)&out[(row0 + row) * 1024 + n0 + cc] = hy4;
    }
}

// ---------------- launch ----------------
extern "C" void kernel_launch(void* const* d_in, const int* in_sizes, int n_in,
                              void* d_out, int out_size, void* d_ws, size_t ws_size,
                              hipStream_t stream) {
    const float* input = (const float*)d_in[0];
    const float* hx    = (const float*)d_in[1];
    const float* cx    = (const float*)d_in[2];
    const float* att   = (const float*)d_in[3];
    const float* w_ih  = (const float*)d_in[4];
    const float* w_hh  = (const float*)d_in[5];
    const float* b_ih  = (const float*)d_in[6];
    const float* b_hh  = (const float*)d_in[7];
    const float* w_att = (const float*)d_in[8];
    const float* b_att = (const float*)d_in[9];
    float* out = (float*)d_out;

    char* ws = (char*)d_ws;
    unsigned short* XH   = (unsigned short*)(ws);                    // 8192x2048 bf16 (32MB)
    unsigned short* ATTb = (unsigned short*)(ws + 33554432);         // 8192x1024 bf16 (16MB)
    unsigned short* W4   = (unsigned short*)(ws + 50331648);         // 4096x2048 bf16 (16MB)
    unsigned short* WA   = (unsigned short*)(ws + 67108864);         // 2048x1024 bf16 (4MB)
    float* bias4         = (float*)(ws + 71303168);                  // 4096 f32

    cast_all_k<<<8704, 256, 0, stream>>>(input, hx, att, w_ih, w_hh, w_att,
                                         b_ih, b_hh, XH, ATTb, W4, WA, bias4);
    fused_gemm_k<<<512, 512, 0, stream>>>(XH, W4, ATTb, WA, bias4, b_att, cx, out);
}

// Round 4
// 384.733 us; speedup vs baseline: 1.0993x; 1.0440x over previous
//
#include <hip/hip_runtime.h>

// LSTMCell with attention, MI355X gfx950.
// Round 8: register diet. R7 gates loop demanded ~288 unified regs/wave
// (128 VGPR + acc[8][4]=128 AGPR + attp=32) against the 256 budget at
// 2 waves/SIMD -> allocator shuffle traffic (VALUBusy 25% in a VALU-free
// loop) capped MfmaUtil at 33%. Fix: attp -> global bf16 scratch (attS),
// written after the att phase, re-read in the epilogue (L2-resident per
// XCD). Everything else identical to R7: m201 quadrant order, R4C8
// concurrency swizzle, LDS-coalesced epilogue, counted vmcnt.

typedef __attribute__((ext_vector_type(8))) __bf16 bf16x8;
typedef __attribute__((ext_vector_type(8))) unsigned short ushort8;
typedef __attribute__((ext_vector_type(4))) float f32x4;

#define AS1 __attribute__((address_space(1)))
#define AS3 __attribute__((address_space(3)))

__device__ __forceinline__ void gld16(const unsigned short* g, unsigned short* l) {
    __builtin_amdgcn_global_load_lds((const AS1 void*)g, (AS3 void*)l, 16, 0, 0);
}

__device__ __forceinline__ unsigned short f2bf(float f) {
    unsigned int u = __builtin_bit_cast(unsigned int, f);
    u += 0x7fffu + ((u >> 16) & 1u);   // RNE
    return (unsigned short)(u >> 16);
}

__device__ __forceinline__ float bf2f(unsigned short u) {
    unsigned int x = ((unsigned int)u) << 16;
    return __builtin_bit_cast(float, x);
}

__device__ __forceinline__ float sigmoidf_(float x) { return 1.f / (1.f + __expf(-x)); }
__device__ __forceinline__ float tanhf_(float x) {
    float e = __expf(-2.f * fabsf(x));
    float t = (1.f - e) / (1.f + e);
    return x >= 0.f ? t : -t;
}

__device__ __forceinline__ bf16x8 ldfrag(const unsigned short* p) {
    return __builtin_bit_cast(bf16x8, *(const ushort8*)p);
}

#define BARRIER __builtin_amdgcn_s_barrier()
#define LGKM0   asm volatile("s_waitcnt lgkmcnt(0)" ::: "memory")
#define VMW_(n) asm volatile("s_waitcnt vmcnt(" #n ")" ::: "memory")
#define VMW(n)  VMW_(n)
#define PRIO1   __builtin_amdgcn_s_setprio(1)
#define PRIO0   __builtin_amdgcn_s_setprio(0)
#define MFMA16(a, b, c) __builtin_amdgcn_mfma_f32_16x16x32_bf16(a, b, c, 0, 0, 0)

// ---------------- fused cast/pack + bias kernel (BW-bound, ~33us) ----------------
__global__ void cast_all_k(const float* __restrict__ input, const float* __restrict__ hx,
                           const float* __restrict__ att,   const float* __restrict__ w_ih,
                           const float* __restrict__ w_hh,  const float* __restrict__ w_att,
                           const float* __restrict__ b_ih,  const float* __restrict__ b_hh,
                           unsigned short* __restrict__ XH, unsigned short* __restrict__ ATTb,
                           unsigned short* __restrict__ W4, unsigned short* __restrict__ WA,
                           float* __restrict__ bias4)
{
    int gid = blockIdx.x * blockDim.x + threadIdx.x;
    if (gid < 4096) bias4[gid] = b_ih[gid] + b_hh[gid];
    const int total = 4456448;  // total float8 units
    for (int i = gid; i < total; i += gridDim.x * blockDim.x) {
        const float* src; unsigned short* dst; int ld, off, rel;
        if (i < 1048576)      { src = input; dst = XH;   ld = 2048; off = 0;    rel = i; }
        else if (i < 2097152) { src = hx;    dst = XH;   ld = 2048; off = 1024; rel = i - 1048576; }
        else if (i < 3145728) { src = att;   dst = ATTb; ld = 1024; off = 0;    rel = i - 2097152; }
        else if (i < 3670016) { src = w_ih;  dst = W4;   ld = 2048; off = 0;    rel = i - 3145728; }
        else if (i < 4194304) { src = w_hh;  dst = W4;   ld = 2048; off = 1024; rel = i - 3670016; }
        else                  { src = w_att; dst = WA;   ld = 1024; off = 0;    rel = i - 4194304; }
        int e = rel * 8;
        int r = e >> 10, c = e & 1023;   // all sources have 1024 fp32 cols
        const float4 v0 = *(const float4*)(src + e);
        const float4 v1 = *(const float4*)(src + e + 4);
        ushort8 p;
        p[0] = f2bf(v0.x); p[1] = f2bf(v0.y); p[2] = f2bf(v0.z); p[3] = f2bf(v0.w);
        p[4] = f2bf(v1.x); p[5] = f2bf(v1.y); p[6] = f2bf(v1.z); p[7] = f2bf(v1.w);
        *(ushort8*)(dst + r * ld + off + c) = p;
    }
}

// ---------------- fused GEMM + full LSTM epilogue ----------------
__global__ __launch_bounds__(512, 2) void fused_gemm_k(
    const unsigned short* __restrict__ XH, const unsigned short* __restrict__ W4,
    const unsigned short* __restrict__ ATTb, const unsigned short* __restrict__ WA,
    const float* __restrict__ bias4, const float* __restrict__ bias_att,
    const float* __restrict__ cx, unsigned short* __restrict__ attS,
    float* __restrict__ out)
{
    __shared__ unsigned short As[2][16384];   // 2 x 32KB
    __shared__ unsigned short Bs[2][16384];   // 2 x 32KB

    const int tid  = threadIdx.x;
    const int wave = tid >> 6, lane = tid & 63;
    const int l15 = lane & 15, quad = lane >> 4;
    const int wr = wave >> 2, wn = wave & 3;

    // R4C8 swizzle: XCD = orig&7 owns row panels xcd*4..xcd*4+3 across all 16
    // col panels. Concurrent 32 blocks/XCD = 4 row panels x 8 col panels.
    const int orig  = blockIdx.x;
    const int xcd   = orig & 7, local = orig >> 3;
    const int row0  = (xcd * 4 + (local & 3)) * 256;   // 32 row panels
    const int n0    = (local >> 2) * 64;               // 16 col panels

    // ---- staging geometry: thread t stages LDS chunk (tid + p*512) of each half
    const int rl = tid >> 3;                         // 0..63
    const int c8 = (tid & 7) ^ (rl & 7);             // source k-chunk (swizzled)
    unsigned aG = (unsigned)(row0 + rl) * 2048u + (unsigned)c8 * 8u;
    unsigned bG = (unsigned)(((rl >> 4) & 3) * 1024 + n0 + (rl & 15)) * 2048u + (unsigned)c8 * 8u;
    unsigned aA = (unsigned)(row0 + rl) * 1024u + (unsigned)c8 * 8u;
    unsigned bA = (unsigned)(((rl >> 4) & 1) * 1024 + n0 + ((rl >> 5) & 1) * 16 + (rl & 15)) * 1024u
                  + (unsigned)c8 * 8u;

    auto stageA_att = [&](int buf) {   // 4 loads: 256x64 A tile
#pragma unroll
        for (int h = 0; h < 2; ++h)
#pragma unroll
            for (int p = 0; p < 2; ++p)
                gld16(ATTb + aA + (unsigned)(h * 131072 + p * 65536),
                      &As[buf][h * 8192 + (tid + p * 512) * 8]);
        aA += 64;
    };
    auto stageB_att = [&](int buf) {   // 2 loads: 128x64 B tile
#pragma unroll
        for (int h = 0; h < 2; ++h)
            gld16(WA + bA + (unsigned)(h * 32768), &Bs[buf][(h * 512 + tid) * 8]);
        bA += 64;
    };
    auto stageA_g = [&](int buf) {     // 4 loads: 256x64 A tile
#pragma unroll
        for (int h = 0; h < 2; ++h)
#pragma unroll
            for (int p = 0; p < 2; ++p)
                gld16(XH + aG + (unsigned)(h * 262144 + p * 131072),
                      &As[buf][h * 8192 + (tid + p * 512) * 8]);
        aG += 64;
    };
    auto stageB_g = [&](int buf) {     // 4 loads: 256x64 B tile
#pragma unroll
        for (int h = 0; h < 2; ++h)
#pragma unroll
            for (int p = 0; p < 2; ++p)
                gld16(W4 + bG + (unsigned)(h * 65536 + p * 32768),
                      &Bs[buf][h * 8192 + (tid + p * 512) * 8]);
        bG += 64;
    };

    // fragment read constants (lane-local)
    const int swz0 = (quad ^ (l15 & 7)) * 8;
    const int swz1 = ((4 + quad) ^ (l15 & 7)) * 8;
    const int aro  = (wr * 128 + l15) * 64;
    const int brG  = (wn * 64 + l15) * 64;
    const int brA  = (wn * 32 + l15) * 64;

    const f32x4 z = {0.f, 0.f, 0.f, 0.f};
    const int col = n0 + wn * 16 + l15;

    // ================= phase A: att GEMM, K=1024 (8 pairs of BK=64 tiles) =========
    {
        f32x4 acc2[8][2];
#pragma unroll
        for (int i = 0; i < 8; ++i) { acc2[i][0] = z; acc2[i][1] = z; }

        auto att_slice = [&](int buf, int sw) {   // reads + 16 MFMA for one k-slice
            bf16x8 aS[8], bS[2];
#pragma unroll
            for (int i = 0; i < 8; ++i) aS[i] = ldfrag(&As[buf][aro + i * 1024 + sw]);
#pragma unroll
            for (int j = 0; j < 2; ++j) bS[j] = ldfrag(&Bs[buf][brA + j * 1024 + sw]);
            BARRIER; LGKM0;
            PRIO1;
#pragma unroll
            for (int i = 0; i < 8; ++i)
#pragma unroll
                for (int j = 0; j < 2; ++j)
                    acc2[i][j] = MFMA16(aS[i], bS[j], acc2[i][j]);
            PRIO0;
            BARRIER;
        };

        stageA_att(0); stageB_att(0);            // tile0 -> buf0
        for (int g = 0; g < 8; ++g) {
            // stage odd tile (2g+1) -> buf1 (quiescent since prev pair's last barrier)
            stageA_att(1); stageB_att(1);
            VMW(6); BARRIER;                     // even tile landed everywhere
            att_slice(0, swz0);
            att_slice(0, swz1);                  // buf0 fully read at its barrier
            // stage next even tile (2g+2) -> buf0
            if (g < 7) { stageA_att(0); stageB_att(0); VMW(6); }
            else       { VMW(0); }
            BARRIER;                             // odd tile landed everywhere
            att_slice(1, swz0);
            att_slice(1, swz1);                  // buf1 quiescent for next g
        }

        // collapse att accumulators -> attS (global bf16 scratch). Frees acc2's
        // 64 AGPR + what was attp's 32 regs for the whole gates loop.
        const float ba0 = bias_att[col], ba1 = bias_att[1024 + col];
#pragma unroll
        for (int i = 0; i < 8; ++i) {
            const int lr = wr * 128 + i * 16 + quad * 4;
#pragma unroll
            for (int r = 0; r < 4; ++r) {
                float v = sigmoidf_(acc2[i][0][r] + ba0) * tanhf_(acc2[i][1][r] + ba1);
                attS[(unsigned)(row0 + lr + r) * 1024u + (unsigned)col] = f2bf(v);
            }
        }
    }

    // ================= phase B: gates GEMM, K=2048 (32 tiles of BK=64) =============
    f32x4 acc[8][4];
#pragma unroll
    for (int i = 0; i < 8; ++i)
#pragma unroll
        for (int j = 0; j < 4; ++j) acc[i][j] = z;

    // m201 quadrant order: P1 rf0-3 x cf0-1 (12 reads), P2 rf0-3 x cf2-3 (4),
    // P3 rf4-7 x cf2-3 (8, stageB), P4 rf4-7 x cf0-1 (0, stageA; bLo reused).
    auto gates_group = [&](int buf, bool iss) {
        bf16x8 aF0[4], aF1[4], aH0[4], aH1[4], bL0[2], bL1[2], bH0[2], bH1[2];
        // P1
#pragma unroll
        for (int i = 0; i < 4; ++i) {
            aF0[i] = ldfrag(&As[buf][aro + i * 1024 + swz0]);
            aF1[i] = ldfrag(&As[buf][aro + i * 1024 + swz1]);
        }
#pragma unroll
        for (int j = 0; j < 2; ++j) {
            bL0[j] = ldfrag(&Bs[buf][brG + j * 1024 + swz0]);
            bL1[j] = ldfrag(&Bs[buf][brG + j * 1024 + swz1]);
        }
        BARRIER; LGKM0;
        PRIO1;
#pragma unroll
        for (int i = 0; i < 4; ++i)
#pragma unroll
            for (int j = 0; j < 2; ++j) {
                acc[i][j] = MFMA16(aF0[i], bL0[j], acc[i][j]);
                acc[i][j] = MFMA16(aF1[i], bL1[j], acc[i][j]);
            }
        PRIO0;
        BARRIER;
        // P2
#pragma unroll
        for (int j = 0; j < 2; ++j) {
            bH0[j] = ldfrag(&Bs[buf][brG + (2 + j) * 1024 + swz0]);
            bH1[j] = ldfrag(&Bs[buf][brG + (2 + j) * 1024 + swz1]);
        }
        BARRIER; LGKM0;
        PRIO1;
#pragma unroll
        for (int i = 0; i < 4; ++i)
#pragma unroll
            for (int j = 0; j < 2; ++j) {
                acc[i][2 + j] = MFMA16(aF0[i], bH0[j], acc[i][2 + j]);
                acc[i][2 + j] = MFMA16(aF1[i], bH1[j], acc[i][2 + j]);
            }
        PRIO0;
        BARRIER;
        // P3 (B region fully read after P2's barrier -> stageB safe)
#pragma unroll
        for (int i = 0; i < 4; ++i) {
            aH0[i] = ldfrag(&As[buf][aro + (4 + i) * 1024 + swz0]);
            aH1[i] = ldfrag(&As[buf][aro + (4 + i) * 1024 + swz1]);
        }
        if (iss) stageB_g(buf);
        BARRIER; LGKM0;
        PRIO1;
#pragma unroll
        for (int i = 0; i < 4; ++i)
#pragma unroll
            for (int j = 0; j < 2; ++j) {
                acc[4 + i][2 + j] = MFMA16(aH0[i], bH0[j], acc[4 + i][2 + j]);
                acc[4 + i][2 + j] = MFMA16(aH1[i], bH1[j], acc[4 + i][2 + j]);
            }
        PRIO0;
        BARRIER;
        // P4 (A region fully read after P3's barrier -> stageA safe); pure MFMA
        if (iss) stageA_g(buf);
        PRIO1;
#pragma unroll
        for (int i = 0; i < 4; ++i)
#pragma unroll
            for (int j = 0; j < 2; ++j) {
                acc[4 + i][j] = MFMA16(aH0[i], bL0[j], acc[4 + i][j]);
                acc[4 + i][j] = MFMA16(aH1[i], bL1[j], acc[4 + i][j]);
            }
        PRIO0;
    };

    stageA_g(0); stageB_g(0); stageA_g(1); stageB_g(1);   // tiles 0,1
    VMW(8); BARRIER;                                      // tile0 landed; tile1 in flight
#pragma unroll 2
    for (int t = 0; t < 30; ++t) {
        gates_group(t & 1, true);
        VMW(8); BARRIER;                                  // tile t+1 landed; t+2 in flight
    }
    gates_group(0, false); VMW(0); BARRIER;               // drain tile31
    gates_group(1, false);
    BARRIER;                                              // all LDS reads done before reuse

    // ---- epilogue: LSTM cell, coalesced via LDS ----
    // LDS reuse: sF (As, 64KB) holds fg then cy; sC (Bs, 64KB) holds cyP then og.
    float* sF = (float*)(&As[0][0]);
    float* sC = (float*)(&Bs[0][0]);
    const float bi  = bias4[col];
    const float bff = bias4[1024 + col];
    const float bg  = bias4[2048 + col];
    const float bo  = bias4[3072 + col];
    const int lcol  = wn * 16 + l15;
    const int CYOFF = 8192 * 1024;

    // step1: per-thread layout -> LDS (fg, cyP); col XOR'd by row bit2 (2-way banks)
#pragma unroll
    for (int i = 0; i < 8; ++i)
#pragma unroll
        for (int r = 0; r < 4; ++r) {
            const int lr = wr * 128 + i * 16 + quad * 4 + r;
            const int pc = lcol ^ (((lr >> 2) & 1) << 4);
            const float attv = bf2f(attS[(unsigned)(row0 + lr) * 1024u + (unsigned)col]);
            sF[lr * 64 + pc] = sigmoidf_(acc[i][1][r] + bff);
            sC[lr * 64 + pc] = sigmoidf_(acc[i][0][r] + bi) * tanhf_(acc[i][2][r] + bg)
                               + attv;
        }
    BARRIER;

    // step2: coalesced cy = fg*cx + cyP; write cy back into sF
    const int rr = tid >> 4;              // 0..31
    const int cc = (tid & 15) * 4;        // 0..60
#pragma unroll
    for (int p = 0; p < 8; ++p) {
        const int row = p * 32 + rr;
        const int pcc = cc ^ (((row >> 2) & 1) << 4);
        f32x4 fg4 = *(f32x4*)&sF[row * 64 + pcc];
        f32x4 cp4 = *(f32x4*)&sC[row * 64 + pcc];
        const float4 cx4 = *(const float4*)&cx[(row0 + row) * 1024 + n0 + cc];
        f32x4 cy4;
        cy4[0] = fg4[0] * cx4.x + cp4[0];
        cy4[1] = fg4[1] * cx4.y + cp4[1];
        cy4[2] = fg4[2] * cx4.z + cp4[2];
        cy4[3] = fg4[3] * cx4.w + cp4[3];
        *(f32x4*)&out[CYOFF + (row0 + row) * 1024 + n0 + cc] = cy4;
        *(f32x4*)&sF[row * 64 + pcc] = cy4;
    }
    BARRIER;

    // step3: per-thread og -> sC (cyP slots dead)
#pragma unroll
    for (int i = 0; i < 8; ++i)
#pragma unroll
        for (int r = 0; r < 4; ++r) {
            const int lr = wr * 128 + i * 16 + quad * 4 + r;
            const int pc = lcol ^ (((lr >> 2) & 1) << 4);
            sC[lr * 64 + pc] = sigmoidf_(acc[i][3][r] + bo);
        }
    BARRIER;

    // step4: coalesced hy = og * tanh(cy)
#pragma unroll
    for (int p = 0; p < 8; ++p) {
        const int row = p * 32 + rr;
        const int pcc = cc ^ (((row >> 2) & 1) << 4);
        f32x4 og4 = *(f32x4*)&sC[row * 64 + pcc];
        f32x4 cy4 = *(f32x4*)&sF[row * 64 + pcc];
        f32x4 hy4;
        hy4[0] = og4[0] * tanhf_(cy4[0]);
        hy4[1] = og4[1] * tanhf_(cy4[1]);
        hy4[2] = og4[2] * tanhf_(cy4[2]);
        hy4[3] = og4[3] * tanhf_(cy4[3]);
        *(f32x4*)&out[(row0 + row) * 1024 + n0 + cc] = hy4;
    }
}

// ---------------- launch ----------------
extern "C" void kernel_launch(void* const* d_in, const int* in_sizes, int n_in,
                              void* d_out, int out_size, void* d_ws, size_t ws_size,
                              hipStream_t stream) {
    const float* input = (const float*)d_in[0];
    const float* hx    = (const float*)d_in[1];
    const float* cx    = (const float*)d_in[2];
    const float* att   = (const float*)d_in[3];
    const float* w_ih  = (const float*)d_in[4];
    const float* w_hh  = (const float*)d_in[5];
    const float* b_ih  = (const float*)d_in[6];
    const float* b_hh  = (const float*)d_in[7];
    const float* w_att = (const float*)d_in[8];
    const float* b_att = (const float*)d_in[9];
    float* out = (float*)d_out;

    char* ws = (char*)d_ws;
    unsigned short* XH   = (unsigned short*)(ws);                    // 8192x2048 bf16 (32MB)
    unsigned short* ATTb = (unsigned short*)(ws + 33554432);         // 8192x1024 bf16 (16MB)
    unsigned short* W4   = (unsigned short*)(ws + 50331648);         // 4096x2048 bf16 (16MB)
    unsigned short* WA   = (unsigned short*)(ws + 67108864);         // 2048x1024 bf16 (4MB)
    float* bias4         = (float*)(ws + 71303168);                  // 4096 f32 (16KB)
    unsigned short* attS = (unsigned short*)(ws + 71319552);         // 8192x1024 bf16 (16MB)

    cast_all_k<<<8704, 256, 0, stream>>>(input, hx, att, w_ih, w_hh, w_att,
                                         b_ih, b_hh, XH, ATTb, W4, WA, bias4);
    fused_gemm_k<<<512, 512, 0, stream>>>(XH, W4, ATTb, WA, bias4, b_att, cx, attS, out);
}